// Round 1
// baseline (1068.913 us; speedup 1.0000x reference)
//
#include <hip/hip_runtime.h>

// MMHSA Matryoshka attention, B=4, S=2048, D=2048, slices {512,1024,1536,2048}.
// Staged pipeline, all matmuls bf16 MFMA (16x16x32), NT-only GEMM (m97 structure).
// Workspace layout (needs 201.3 MB):
//   R = 33554432 bytes
//   [0,R):    xb (bf16 x)          -> reused as attn[4 slices] during attention
//   [R,2R):   WqT WkT WvT WoT bf16 -> WqT/WkT overlaid by f32 cum during attention
//   [2R,3R):  q bf16
//   [3R,4R):  k bf16
//   [4R,5R):  v bf16               -> reused as o after v->vT transpose
//   [5R,6R):  vT bf16

typedef __attribute__((ext_vector_type(8))) short bf16x8;
typedef __attribute__((ext_vector_type(4))) float f32x4;
typedef unsigned short u16;
typedef unsigned int u32;

#define DEV __device__ __forceinline__

DEV u16 f2bf(float f) {
  union { float f; u32 u; } v; v.f = f;
  u32 r = v.u + 0x7fffu + ((v.u >> 16) & 1u);
  return (u16)(r >> 16);
}

struct alignas(16) U16x8 { u16 v[8]; };

// ---------------- conversion / transpose kernels ----------------

__global__ __launch_bounds__(256) void conv_f32_bf16(const float* __restrict__ in,
                                                     u16* __restrict__ out) {
  size_t i = ((size_t)blockIdx.x * 256 + threadIdx.x) * 8;
  float4 a = *(const float4*)(in + i);
  float4 b = *(const float4*)(in + i + 4);
  U16x8 w;
  w.v[0] = f2bf(a.x); w.v[1] = f2bf(a.y); w.v[2] = f2bf(a.z); w.v[3] = f2bf(a.w);
  w.v[4] = f2bf(b.x); w.v[5] = f2bf(b.y); w.v[6] = f2bf(b.z); w.v[7] = f2bf(b.w);
  *(U16x8*)(out + i) = w;
}

// out[c][r] = bf16(in[r][c]) for 2048x2048 f32 weight
__global__ __launch_bounds__(256) void transpose_conv_f32_bf16(const float* __restrict__ in,
                                                               u16* __restrict__ out) {
  const int D = 2048;
  __shared__ float t[32][33];
  int bx = blockIdx.x * 32, by = blockIdx.y * 32;
  int tx = threadIdx.x & 31, ty = threadIdx.x >> 5;
#pragma unroll
  for (int i = 0; i < 32; i += 8)
    t[ty + i][tx] = in[(size_t)(by + ty + i) * D + bx + tx];
  __syncthreads();
#pragma unroll
  for (int i = 0; i < 32; i += 8)
    out[(size_t)(bx + ty + i) * D + by + tx] = f2bf(t[tx][ty + i]);
}

// per-batch 2048x2048 bf16 transpose (grid.z = batch)
__global__ __launch_bounds__(256) void transpose_bf16(const u16* __restrict__ in,
                                                      u16* __restrict__ out) {
  const int D = 2048;
  size_t zoff = (size_t)blockIdx.z * D * D;
  in += zoff; out += zoff;
  __shared__ u16 t[32][34];
  int bx = blockIdx.x * 32, by = blockIdx.y * 32;
  int tx = threadIdx.x & 31, ty = threadIdx.x >> 5;
#pragma unroll
  for (int i = 0; i < 32; i += 8)
    t[ty + i][tx] = in[(size_t)(by + ty + i) * D + bx + tx];
  __syncthreads();
#pragma unroll
  for (int i = 0; i < 32; i += 8)
    out[(size_t)(bx + ty + i) * D + by + tx] = t[tx][ty + i];
}

// ---------------- NT GEMM: C[M,N] = A[M,K] @ B[N,K]^T ----------------
// 128x128 tile, BK=32, 256 threads (2x2 waves, 64x64 per wave), m97 structure.
// kmode: 0 = plain, 1 = causal QK (skip tiles fully above diagonal),
//        2 = causal PV (truncate K at m0+128; A cols beyond are zeros).
template <bool ACCUM, bool OUT_BF16>
__global__ __launch_bounds__(256) void gemm_nt(
    const u16* __restrict__ A, long long sA, int lda,
    const u16* __restrict__ B, long long sB, int ldb,
    void* __restrict__ Cv, long long sC, int ldc,
    int K, int kmode) {
  const int z = blockIdx.z;
  A += (size_t)z * sA;
  B += (size_t)z * sB;
  const int m0 = blockIdx.y * 128, n0 = blockIdx.x * 128;
  if (kmode == 1 && n0 >= m0 + 128) return;  // fully masked tile
  const int kEnd = (kmode == 2) ? (m0 + 128) : K;

  __shared__ alignas(16) u16 As[128 * 32];
  __shared__ alignas(16) u16 Bs[128 * 32];

  const int tid = threadIdx.x;
  const int lane = tid & 63, wave = tid >> 6;
  const int wm = (wave >> 1) * 64, wn = (wave & 1) * 64;
  const int fr = lane & 15, kc = (lane >> 4) * 8;

  f32x4 acc[4][4];
#pragma unroll
  for (int m = 0; m < 4; ++m)
#pragma unroll
    for (int n = 0; n < 4; ++n)
#pragma unroll
      for (int j = 0; j < 4; ++j) acc[m][n][j] = 0.f;

  for (int k0 = 0; k0 < kEnd; k0 += 32) {
    __syncthreads();  // previous iteration's ds_reads drained before overwrite
#pragma unroll
    for (int r = 0; r < 2; ++r) {
      int c = r * 256 + tid;
      int row = c >> 2, kp = (c & 3) * 8;
      const u16* ga = A + (size_t)(m0 + row) * lda + (k0 + kp);
      const u16* gb = B + (size_t)(n0 + row) * ldb + (k0 + kp);
      u32 lo = (u32)(r * 4096 + wave * 1024);  // wave-uniform LDS base
      __builtin_amdgcn_global_load_lds(
          (const __attribute__((address_space(1))) void*)ga,
          (__attribute__((address_space(3))) void*)((char*)As + lo), 16, 0, 0);
      __builtin_amdgcn_global_load_lds(
          (const __attribute__((address_space(1))) void*)gb,
          (__attribute__((address_space(3))) void*)((char*)Bs + lo), 16, 0, 0);
    }
    __syncthreads();  // vmcnt(0) drained before barrier -> tiles visible
    bf16x8 af[4], bfr[4];
#pragma unroll
    for (int m = 0; m < 4; ++m)
      af[m] = *(const bf16x8*)&As[(wm + m * 16 + fr) * 32 + kc];
#pragma unroll
    for (int n = 0; n < 4; ++n)
      bfr[n] = *(const bf16x8*)&Bs[(wn + n * 16 + fr) * 32 + kc];
#pragma unroll
    for (int m = 0; m < 4; ++m)
#pragma unroll
      for (int n = 0; n < 4; ++n)
        acc[m][n] = __builtin_amdgcn_mfma_f32_16x16x32_bf16(af[m], bfr[n],
                                                            acc[m][n], 0, 0, 0);
  }

  // epilogue: C/D layout col = lane&15, row = (lane>>4)*4 + reg
  const int col = lane & 15, rb = (lane >> 4) * 4;
  if (OUT_BF16) {
    u16* C = (u16*)Cv + (size_t)z * sC;
#pragma unroll
    for (int m = 0; m < 4; ++m)
#pragma unroll
      for (int n = 0; n < 4; ++n)
#pragma unroll
        for (int j = 0; j < 4; ++j)
          C[(size_t)(m0 + wm + m * 16 + rb + j) * ldc + (n0 + wn + n * 16 + col)] =
              f2bf(acc[m][n][j]);
  } else {
    float* C = (float*)Cv + (size_t)z * sC;
#pragma unroll
    for (int m = 0; m < 4; ++m)
#pragma unroll
      for (int n = 0; n < 4; ++n)
#pragma unroll
        for (int j = 0; j < 4; ++j) {
          size_t idx = (size_t)(m0 + wm + m * 16 + rb + j) * ldc + (n0 + wn + n * 16 + col);
          float val = acc[m][n][j];
          if (ACCUM) val += C[idx];
          C[idx] = val;
        }
  }
}

// ---------------- causal row softmax: f32 cum -> bf16 attn ----------------
__global__ __launch_bounds__(256) void softmax_causal(const float* __restrict__ cum,
                                                      u16* __restrict__ attn,
                                                      float scale) {
  const int S = 2048;
  const int r = blockIdx.x;
  const int tid = threadIdx.x;
  const int lane = tid & 63, wave = tid >> 6;
  const int c0 = tid * 8;
  const int nvalid = r + 1;
  const float* rowp = cum + (size_t)r * S;

  float x[8];
  if (c0 < nvalid) {
    float4 a = *(const float4*)(rowp + c0);
    float4 b = *(const float4*)(rowp + c0 + 4);
    x[0] = a.x; x[1] = a.y; x[2] = a.z; x[3] = a.w;
    x[4] = b.x; x[5] = b.y; x[6] = b.z; x[7] = b.w;
  } else {
#pragma unroll
    for (int i = 0; i < 8; ++i) x[i] = 0.f;
  }

  float mx = -3e38f;
#pragma unroll
  for (int i = 0; i < 8; ++i) {
    if (c0 + i < nvalid) { x[i] *= scale; mx = fmaxf(mx, x[i]); }
  }
#pragma unroll
  for (int off = 32; off > 0; off >>= 1) mx = fmaxf(mx, __shfl_xor(mx, off));
  __shared__ float redm[4], reds[4];
  if (lane == 0) redm[wave] = mx;
  __syncthreads();
  mx = fmaxf(fmaxf(redm[0], redm[1]), fmaxf(redm[2], redm[3]));

  float e[8], sum = 0.f;
#pragma unroll
  for (int i = 0; i < 8; ++i) {
    e[i] = (c0 + i < nvalid) ? __expf(x[i] - mx) : 0.f;
    sum += e[i];
  }
#pragma unroll
  for (int off = 32; off > 0; off >>= 1) sum += __shfl_xor(sum, off);
  if (lane == 0) reds[wave] = sum;
  __syncthreads();
  sum = reds[0] + reds[1] + reds[2] + reds[3];
  float inv = 1.f / sum;

  U16x8 w;
#pragma unroll
  for (int i = 0; i < 8; ++i) w.v[i] = f2bf(e[i] * inv);
  *(U16x8*)(attn + (size_t)r * S + c0) = w;
}

// ---------------- launcher ----------------
extern "C" void kernel_launch(void* const* d_in, const int* in_sizes, int n_in,
                              void* d_out, int out_size, void* d_ws, size_t ws_size,
                              hipStream_t stream) {
  (void)in_sizes; (void)n_in; (void)out_size; (void)ws_size;
  const float* x  = (const float*)d_in[0];
  // d_in[1] is the boolean causal mask; causality is hard-coded.
  const float* Wq = (const float*)d_in[2];
  const float* Wk = (const float*)d_in[3];
  const float* Wv = (const float*)d_in[4];
  const float* Wo = (const float*)d_in[5];
  float* out = (float*)d_out;

  char* w = (char*)d_ws;
  const size_t R  = 33554432ull;   // 32 MiB region
  const size_t WE = 4194304ull;    // 2048*2048 elems

  u16* xb  = (u16*)(w);
  u16* wqT = (u16*)(w + R);
  u16* wkT = wqT + WE;
  u16* wvT = wkT + WE;
  u16* woT = wvT + WE;
  u16* q   = (u16*)(w + 2 * R);
  u16* kk  = (u16*)(w + 3 * R);
  u16* v   = (u16*)(w + 4 * R);
  u16* vT  = (u16*)(w + 5 * R);
  u16* o   = v;                    // v dead after transpose
  float* cum  = (float*)(w + R);   // overlays WqT+WkT (dead after projections)
  u16*   attn = (u16*)(w);         // overlays xb (dead after projections)

  // 1) x -> bf16
  conv_f32_bf16<<<8192, 256, 0, stream>>>(x, xb);
  // 2) weights -> transposed bf16
  dim3 tg(64, 64);
  transpose_conv_f32_bf16<<<tg, 256, 0, stream>>>(Wq, wqT);
  transpose_conv_f32_bf16<<<tg, 256, 0, stream>>>(Wk, wkT);
  transpose_conv_f32_bf16<<<tg, 256, 0, stream>>>(Wv, wvT);
  transpose_conv_f32_bf16<<<tg, 256, 0, stream>>>(Wo, woT);
  // 3) q,k,v projections, fused over grid.z (B matrices and C outputs contiguous)
  gemm_nt<false, true><<<dim3(16, 64, 3), 256, 0, stream>>>(
      xb, 0LL, 2048, wqT, (long long)WE, 2048, q, 16777216LL, 2048, 2048, 0);
  // 4) v -> vT (per batch)
  transpose_bf16<<<dim3(64, 64, 4), 256, 0, stream>>>(v, vT);
  // 5) attention, per batch
  for (int b = 0; b < 4; ++b) {
    const u16* qb = q  + (size_t)b * WE;
    const u16* kb = kk + (size_t)b * WE;
    for (int s = 0; s < 4; ++s) {
      if (s == 0)
        gemm_nt<false, false><<<dim3(16, 16), 256, 0, stream>>>(
            qb + s * 512, 0LL, 2048, kb + s * 512, 0LL, 2048,
            cum, 0LL, 2048, 512, 1);
      else
        gemm_nt<true, false><<<dim3(16, 16), 256, 0, stream>>>(
            qb + s * 512, 0LL, 2048, kb + s * 512, 0LL, 2048,
            cum, 0LL, 2048, 512, 1);
      float scale = 1.0f / sqrtf(512.0f * (float)(s + 1));
      softmax_causal<<<2048, 256, 0, stream>>>(cum, attn + (size_t)s * WE, scale);
    }
    // PV: z = slice; o columns [512z, 512z+512)
    gemm_nt<false, true><<<dim3(4, 16, 4), 256, 0, stream>>>(
        attn, (long long)WE, 2048,
        vT + (size_t)b * WE, 1048576LL, 2048,
        o + (size_t)b * WE, 512LL, 2048, 2048, 2);
  }
  // 6) out = o @ Wo
  gemm_nt<false, false><<<dim3(16, 64), 256, 0, stream>>>(
      o, 0LL, 2048, woT, 0LL, 2048, out, 0LL, 2048, 2048, 0);
}

// Round 2
// 786.056 us; speedup vs baseline: 1.3598x; 1.3598x over previous
//
#include <hip/hip_runtime.h>

// MMHSA Matryoshka attention, B=4, S=2048, D=2048, slices {512,1024,1536,2048}.
// All matmuls bf16 MFMA 16x16x32, NT GEMM, 128^2 tile, BK=32, double-buffered
// LDS with stage-ahead (T3-minimum 2-phase), XCD-chunked swizzle on big GEMMs.
//
// Workspace layout (R = 32 MiB, total 6R = 201.3 MB):
//   reg0 [0,R):    xb (bf16 x)            -> attn_s (per-slice, 4 batches) later
//   reg1 [R,2R):   wqT wkT wvT woT bf16   (preserved all run)
//   reg2 [2R,3R):  q  (4 batches)
//   reg3 [3R,4R):  k
//   reg4 [4R,5R):  v -> o (v dead after transpose)
//   reg5 [5R,6R):  vT
// cum (f32, 4 batches x S x S = 67 MB) lives in d_out until the final GEMM.

typedef __attribute__((ext_vector_type(8))) short bf16x8;
typedef __attribute__((ext_vector_type(4))) float f32x4;
typedef unsigned short u16;
typedef unsigned int u32;

__device__ __forceinline__ u16 f2bf(float f) {
  union { float f; u32 u; } v; v.f = f;
  u32 r = v.u + 0x7fffu + ((v.u >> 16) & 1u);
  return (u16)(r >> 16);
}
struct alignas(16) U16x8 { u16 v[8]; };

// ---------------- conversion / transpose kernels ----------------

__global__ __launch_bounds__(256) void conv_f32_bf16(const float* __restrict__ in,
                                                     u16* __restrict__ out) {
  size_t i = ((size_t)blockIdx.x * 256 + threadIdx.x) * 8;
  float4 a = *(const float4*)(in + i);
  float4 b = *(const float4*)(in + i + 4);
  U16x8 w;
  w.v[0] = f2bf(a.x); w.v[1] = f2bf(a.y); w.v[2] = f2bf(a.z); w.v[3] = f2bf(a.w);
  w.v[4] = f2bf(b.x); w.v[5] = f2bf(b.y); w.v[6] = f2bf(b.z); w.v[7] = f2bf(b.w);
  *(U16x8*)(out + i) = w;
}

// out[z][c][r] = bf16(Wz[r][c]) for four 2048x2048 f32 weights, z = blockIdx.z
__global__ __launch_bounds__(256) void transpose_conv4(const float* __restrict__ W0,
                                                       const float* __restrict__ W1,
                                                       const float* __restrict__ W2,
                                                       const float* __restrict__ W3,
                                                       u16* __restrict__ out) {
  const int D = 2048;
  const float* in = (blockIdx.z == 0) ? W0 : (blockIdx.z == 1) ? W1
                  : (blockIdx.z == 2) ? W2 : W3;
  u16* o = out + (size_t)blockIdx.z * D * D;
  __shared__ float t[32][33];
  int bx = blockIdx.x * 32, by = blockIdx.y * 32;
  int tx = threadIdx.x & 31, ty = threadIdx.x >> 5;
#pragma unroll
  for (int i = 0; i < 32; i += 8)
    t[ty + i][tx] = in[(size_t)(by + ty + i) * D + bx + tx];
  __syncthreads();
#pragma unroll
  for (int i = 0; i < 32; i += 8)
    o[(size_t)(bx + ty + i) * D + by + tx] = f2bf(t[tx][ty + i]);
}

// per-batch 2048x2048 bf16 transpose (grid.z = batch)
__global__ __launch_bounds__(256) void transpose_bf16(const u16* __restrict__ in,
                                                      u16* __restrict__ out) {
  const int D = 2048;
  size_t zoff = (size_t)blockIdx.z * D * D;
  in += zoff; out += zoff;
  __shared__ u16 t[32][34];
  int bx = blockIdx.x * 32, by = blockIdx.y * 32;
  int tx = threadIdx.x & 31, ty = threadIdx.x >> 5;
#pragma unroll
  for (int i = 0; i < 32; i += 8)
    t[ty + i][tx] = in[(size_t)(by + ty + i) * D + bx + tx];
  __syncthreads();
#pragma unroll
  for (int i = 0; i < 32; i += 8)
    out[(size_t)(bx + ty + i) * D + by + tx] = t[tx][ty + i];
}

// ---------------- NT GEMM: C[M,N] = A[M,K] @ B[N,K]^T ----------------
// kmode: 0 plain, 1 causal QK (skip tiles above diagonal), 2 causal PV
//        (truncate K at m0+128). flat: 1-D grid, XCD-chunked, mat fastest.
template <bool ACCUM, bool OUT_BF16>
__global__ __launch_bounds__(256) void gemm_nt(
    const u16* __restrict__ A, long long sA, int lda,
    const u16* __restrict__ B, long long sB, int ldb,
    void* __restrict__ Cv, long long sC, int ldc,
    int K, int kmode,
    int nmat, int ntn, int flat, long long sBm, long long sCm) {
  int n0, m0, mat = 0;
  if (flat) {
    u32 wg = blockIdx.x;
    u32 nchunk = gridDim.x >> 3;                  // grid.x % 8 == 0 required
    u32 swz = (wg & 7u) * nchunk + (wg >> 3);     // contiguous chunk per XCD
    mat = (int)(swz % (u32)nmat);
    u32 t = swz / (u32)nmat;
    n0 = (int)(t % (u32)ntn) * 128;
    m0 = (int)(t / (u32)ntn) * 128;
  } else {
    n0 = blockIdx.x * 128;
    m0 = blockIdx.y * 128;
  }
  const int z = blockIdx.z;
  if (kmode == 1 && n0 >= m0 + 128) return;       // fully masked tile
  const int kEnd = (kmode == 2) ? (m0 + 128) : K;

  A += (size_t)z * sA;
  B += (size_t)z * sB + (size_t)mat * sBm;

  __shared__ alignas(16) u16 As[2][128 * 32];
  __shared__ alignas(16) u16 Bs[2][128 * 32];

  const int tid = threadIdx.x;
  const int lane = tid & 63, wave = tid >> 6;
  const int wm = (wave >> 1) * 64, wn = (wave & 1) * 64;
  const int fr = lane & 15, kc = (lane >> 4) * 8;

  // hoisted staging addresses: thread tid covers row (tid>>2), k-col (tid&3)*8
  const u16* ga0 = A + (size_t)(m0 + (tid >> 2)) * lda + (tid & 3) * 8;
  const u16* ga1 = ga0 + (size_t)64 * lda;
  const u16* gb0 = B + (size_t)(n0 + (tid >> 2)) * ldb + (tid & 3) * 8;
  const u16* gb1 = gb0 + (size_t)64 * ldb;
  const u32 lo = (u32)(wave * 1024);              // wave-uniform LDS base

  f32x4 acc[4][4];
#pragma unroll
  for (int m = 0; m < 4; ++m)
#pragma unroll
    for (int n = 0; n < 4; ++n)
#pragma unroll
      for (int j = 0; j < 4; ++j) acc[m][n][j] = 0.f;

#define STAGE(buf, kOff) do {                                                         \
    __builtin_amdgcn_global_load_lds(                                                 \
        (const __attribute__((address_space(1))) void*)(ga0 + (kOff)),                \
        (__attribute__((address_space(3))) void*)((char*)&As[buf][0] + lo), 16, 0, 0);\
    __builtin_amdgcn_global_load_lds(                                                 \
        (const __attribute__((address_space(1))) void*)(ga1 + (kOff)),                \
        (__attribute__((address_space(3))) void*)((char*)&As[buf][0] + lo + 4096), 16, 0, 0);\
    __builtin_amdgcn_global_load_lds(                                                 \
        (const __attribute__((address_space(1))) void*)(gb0 + (kOff)),                \
        (__attribute__((address_space(3))) void*)((char*)&Bs[buf][0] + lo), 16, 0, 0);\
    __builtin_amdgcn_global_load_lds(                                                 \
        (const __attribute__((address_space(1))) void*)(gb1 + (kOff)),                \
        (__attribute__((address_space(3))) void*)((char*)&Bs[buf][0] + lo + 4096), 16, 0, 0);\
  } while (0)

  const int nt = kEnd >> 5;
  STAGE(0, 0);
  for (int t = 0; t < nt; ++t) {
    __syncthreads();  // implicit vmcnt(0): staged tile t visible; prev reads done
    if (t + 1 < nt) STAGE((t + 1) & 1, (t + 1) * 32);  // in flight during MFMAs
    const u16* as = &As[t & 1][0];
    const u16* bs = &Bs[t & 1][0];
    bf16x8 af[4], bfr[4];
#pragma unroll
    for (int m = 0; m < 4; ++m)
      af[m] = *(const bf16x8*)&as[(wm + m * 16 + fr) * 32 + kc];
#pragma unroll
    for (int n = 0; n < 4; ++n)
      bfr[n] = *(const bf16x8*)&bs[(wn + n * 16 + fr) * 32 + kc];
#pragma unroll
    for (int m = 0; m < 4; ++m)
#pragma unroll
      for (int n = 0; n < 4; ++n)
        acc[m][n] = __builtin_amdgcn_mfma_f32_16x16x32_bf16(af[m], bfr[n],
                                                            acc[m][n], 0, 0, 0);
  }
#undef STAGE

  // epilogue: C/D layout col = lane&15, row = (lane>>4)*4 + reg
  const int col = lane & 15, rb = (lane >> 4) * 4;
  if (OUT_BF16) {
    u16* C = (u16*)Cv + (size_t)z * sC + (size_t)mat * sCm;
#pragma unroll
    for (int m = 0; m < 4; ++m)
#pragma unroll
      for (int n = 0; n < 4; ++n)
#pragma unroll
        for (int j = 0; j < 4; ++j)
          C[(size_t)(m0 + wm + m * 16 + rb + j) * ldc + (n0 + wn + n * 16 + col)] =
              f2bf(acc[m][n][j]);
  } else {
    float* C = (float*)Cv + (size_t)z * sC + (size_t)mat * sCm;
#pragma unroll
    for (int m = 0; m < 4; ++m)
#pragma unroll
      for (int n = 0; n < 4; ++n)
#pragma unroll
        for (int j = 0; j < 4; ++j) {
          size_t idx = (size_t)(m0 + wm + m * 16 + rb + j) * ldc + (n0 + wn + n * 16 + col);
          float val = acc[m][n][j];
          if (ACCUM) val += C[idx];
          C[idx] = val;
        }
  }
}

// ---------------- causal row softmax: f32 cum -> bf16 attn (batched) ----------------
__global__ __launch_bounds__(256) void softmax_causal(const float* __restrict__ cum,
                                                      u16* __restrict__ attn,
                                                      float scale) {
  const int S = 2048;
  const size_t WEz = (size_t)S * S * blockIdx.y;
  const int r = blockIdx.x;
  const int tid = threadIdx.x;
  const int lane = tid & 63, wave = tid >> 6;
  const int c0 = tid * 8;
  const int nvalid = r + 1;
  const float* rowp = cum + WEz + (size_t)r * S;

  float x[8];
  if (c0 < nvalid) {
    float4 a = *(const float4*)(rowp + c0);
    float4 b = *(const float4*)(rowp + c0 + 4);
    x[0] = a.x; x[1] = a.y; x[2] = a.z; x[3] = a.w;
    x[4] = b.x; x[5] = b.y; x[6] = b.z; x[7] = b.w;
  } else {
#pragma unroll
    for (int i = 0; i < 8; ++i) x[i] = 0.f;
  }

  float mx = -3e38f;
#pragma unroll
  for (int i = 0; i < 8; ++i) {
    if (c0 + i < nvalid) { x[i] *= scale; mx = fmaxf(mx, x[i]); }
  }
#pragma unroll
  for (int off = 32; off > 0; off >>= 1) mx = fmaxf(mx, __shfl_xor(mx, off));
  __shared__ float redm[4], reds[4];
  if (lane == 0) redm[wave] = mx;
  __syncthreads();
  mx = fmaxf(fmaxf(redm[0], redm[1]), fmaxf(redm[2], redm[3]));

  float e[8], sum = 0.f;
#pragma unroll
  for (int i = 0; i < 8; ++i) {
    e[i] = (c0 + i < nvalid) ? __expf(x[i] - mx) : 0.f;
    sum += e[i];
  }
#pragma unroll
  for (int off = 32; off > 0; off >>= 1) sum += __shfl_xor(sum, off);
  if (lane == 0) reds[wave] = sum;
  __syncthreads();
  sum = reds[0] + reds[1] + reds[2] + reds[3];
  float inv = 1.f / sum;

  U16x8 w;
#pragma unroll
  for (int i = 0; i < 8; ++i) w.v[i] = f2bf(e[i] * inv);
  *(U16x8*)(attn + WEz + (size_t)r * S + c0) = w;
}

// ---------------- launcher ----------------
extern "C" void kernel_launch(void* const* d_in, const int* in_sizes, int n_in,
                              void* d_out, int out_size, void* d_ws, size_t ws_size,
                              hipStream_t stream) {
  (void)in_sizes; (void)n_in; (void)out_size; (void)ws_size;
  const float* x  = (const float*)d_in[0];
  // d_in[1] is the boolean causal mask; causality is hard-coded.
  const float* Wq = (const float*)d_in[2];
  const float* Wk = (const float*)d_in[3];
  const float* Wv = (const float*)d_in[4];
  const float* Wo = (const float*)d_in[5];
  float* out = (float*)d_out;

  char* w = (char*)d_ws;
  const size_t R  = 33554432ull;      // 32 MiB region
  const long long WE = 4194304LL;     // 2048*2048 elems (one batch matrix)

  u16* xb  = (u16*)(w);
  u16* wT  = (u16*)(w + R);           // wqT, wkT, wvT, woT consecutive
  u16* wqT = wT;
  u16* woT = wT + 3 * WE;
  u16* q   = (u16*)(w + 2 * R);
  u16* kk  = (u16*)(w + 3 * R);
  u16* v   = (u16*)(w + 4 * R);
  u16* vT  = (u16*)(w + 5 * R);
  u16* o   = v;                        // v dead after transpose
  u16* attn = xb;                      // xb dead after projections
  float* cum = (float*)d_out;          // d_out dead until final GEMM (67 MB)

  // 1) x -> bf16
  conv_f32_bf16<<<8192, 256, 0, stream>>>(x, xb);
  // 2) weights -> transposed bf16 (one launch, z = which weight)
  transpose_conv4<<<dim3(64, 64, 4), 256, 0, stream>>>(Wq, Wk, Wv, Wo, wT);
  // 3) fused q,k,v projection: flat XCD-chunked grid, matrix index fastest
  gemm_nt<false, true><<<dim3(3072), 256, 0, stream>>>(
      xb, 0LL, 2048, wqT, 0LL, 2048, q, 0LL, 2048, 2048, 0,
      /*nmat*/3, /*ntn*/16, /*flat*/1, /*sBm*/WE, /*sCm*/16777216LL);
  // 4) v -> vT (per batch)
  transpose_bf16<<<dim3(64, 64, 4), 256, 0, stream>>>(v, vT);
  // 5) attention, per slice, batched over z=4 batches
  for (int s = 0; s < 4; ++s) {
    if (s == 0)
      gemm_nt<false, false><<<dim3(16, 16, 4), 256, 0, stream>>>(
          q + s * 512, WE, 2048, kk + s * 512, WE, 2048,
          cum, WE, 2048, 512, 1, 1, 16, 0, 0LL, 0LL);
    else
      gemm_nt<true, false><<<dim3(16, 16, 4), 256, 0, stream>>>(
          q + s * 512, WE, 2048, kk + s * 512, WE, 2048,
          cum, WE, 2048, 512, 1, 1, 16, 0, 0LL, 0LL);
    float scale = 1.0f / sqrtf(512.0f * (float)(s + 1));
    softmax_causal<<<dim3(2048, 4), 256, 0, stream>>>(cum, attn, scale);
    gemm_nt<false, true><<<dim3(4, 16, 4), 256, 0, stream>>>(
        attn, WE, 2048, vT + (size_t)s * 512 * 2048, WE, 2048,
        o + s * 512, WE, 2048, 2048, 2, 1, 4, 0, 0LL, 0LL);
  }
  // 6) out = o @ Wo  (M=8192 rows contiguous across batches)
  gemm_nt<false, false><<<dim3(1024), 256, 0, stream>>>(
      o, 0LL, 2048, woT, 0LL, 2048, out, 0LL, 2048, 2048, 0,
      1, 16, 1, 0LL, 0LL);
}

// Round 3
// 701.994 us; speedup vs baseline: 1.5227x; 1.1197x over previous
//
#include <hip/hip_runtime.h>

// MMHSA Matryoshka attention, B=4, S=2048, D=2048, slices {512,1024,1536,2048}.
// All matmuls bf16 MFMA 16x16x32, NT GEMM, 128^2 tile, BK=32, double-buffered
// LDS with stage-ahead. Attention uses a 2-pass snapshot QK sweep: cum_s are
// K-prefixes of one Q.K^T, dumped as scaled bf16 at each 512-boundary.
//
// Workspace (R = 32 MiB, 6R = 201.3 MB):
//   [0,R):    xb (bf16 x)          -> attn scratch for slice 1
//   [R,2R):   wqT wkT wvT woT bf16
//   [2R,3R):  q   [3R,4R): k   [4R,5R): v -> o   [5R,6R): vT
// cum/attn snapshots (bf16) live in d_out: slot0 = first 33.5MB, slot1 = rest.

typedef __attribute__((ext_vector_type(8))) short bf16x8;
typedef __attribute__((ext_vector_type(4))) float f32x4;
typedef unsigned short u16;
typedef unsigned int u32;

__device__ __forceinline__ u16 f2bf(float f) {
  union { float f; u32 u; } v; v.f = f;
  u32 r = v.u + 0x7fffu + ((v.u >> 16) & 1u);
  return (u16)(r >> 16);
}
__device__ __forceinline__ float bf2f(u16 b) {
  union { u32 u; float f; } v; v.u = ((u32)b) << 16;
  return v.f;
}
struct alignas(16) U16x8 { u16 v[8]; };

// ---------------- conversion / transpose kernels ----------------

__global__ __launch_bounds__(256) void conv_f32_bf16(const float* __restrict__ in,
                                                     u16* __restrict__ out) {
  size_t i = ((size_t)blockIdx.x * 256 + threadIdx.x) * 8;
  float4 a = *(const float4*)(in + i);
  float4 b = *(const float4*)(in + i + 4);
  U16x8 w;
  w.v[0] = f2bf(a.x); w.v[1] = f2bf(a.y); w.v[2] = f2bf(a.z); w.v[3] = f2bf(a.w);
  w.v[4] = f2bf(b.x); w.v[5] = f2bf(b.y); w.v[6] = f2bf(b.z); w.v[7] = f2bf(b.w);
  *(U16x8*)(out + i) = w;
}

__global__ __launch_bounds__(256) void transpose_conv4(const float* __restrict__ W0,
                                                       const float* __restrict__ W1,
                                                       const float* __restrict__ W2,
                                                       const float* __restrict__ W3,
                                                       u16* __restrict__ out) {
  const int D = 2048;
  const float* in = (blockIdx.z == 0) ? W0 : (blockIdx.z == 1) ? W1
                  : (blockIdx.z == 2) ? W2 : W3;
  u16* o = out + (size_t)blockIdx.z * D * D;
  __shared__ float t[32][33];
  int bx = blockIdx.x * 32, by = blockIdx.y * 32;
  int tx = threadIdx.x & 31, ty = threadIdx.x >> 5;
#pragma unroll
  for (int i = 0; i < 32; i += 8)
    t[ty + i][tx] = in[(size_t)(by + ty + i) * D + bx + tx];
  __syncthreads();
#pragma unroll
  for (int i = 0; i < 32; i += 8)
    o[(size_t)(bx + ty + i) * D + by + tx] = f2bf(t[tx][ty + i]);
}

__global__ __launch_bounds__(256) void transpose_bf16(const u16* __restrict__ in,
                                                      u16* __restrict__ out) {
  const int D = 2048;
  size_t zoff = (size_t)blockIdx.z * D * D;
  in += zoff; out += zoff;
  __shared__ u16 t[32][34];
  int bx = blockIdx.x * 32, by = blockIdx.y * 32;
  int tx = threadIdx.x & 31, ty = threadIdx.x >> 5;
#pragma unroll
  for (int i = 0; i < 32; i += 8)
    t[ty + i][tx] = in[(size_t)(by + ty + i) * D + bx + tx];
  __syncthreads();
#pragma unroll
  for (int i = 0; i < 32; i += 8)
    out[(size_t)(bx + ty + i) * D + by + tx] = t[tx][ty + i];
}

// ---------------- staging macro (128x32 bf16 tile, 256 threads) ----------------
#define STAGE4(Abuf, Bbuf, kOff)                                                       \
  do {                                                                                 \
    __builtin_amdgcn_global_load_lds(                                                  \
        (const __attribute__((address_space(1))) void*)(ga0 + (kOff)),                 \
        (__attribute__((address_space(3))) void*)((char*)(Abuf) + lo), 16, 0, 0);      \
    __builtin_amdgcn_global_load_lds(                                                  \
        (const __attribute__((address_space(1))) void*)(ga1 + (kOff)),                 \
        (__attribute__((address_space(3))) void*)((char*)(Abuf) + lo + 4096), 16, 0, 0);\
    __builtin_amdgcn_global_load_lds(                                                  \
        (const __attribute__((address_space(1))) void*)(gb0 + (kOff)),                 \
        (__attribute__((address_space(3))) void*)((char*)(Bbuf) + lo), 16, 0, 0);      \
    __builtin_amdgcn_global_load_lds(                                                  \
        (const __attribute__((address_space(1))) void*)(gb1 + (kOff)),                 \
        (__attribute__((address_space(3))) void*)((char*)(Bbuf) + lo + 4096), 16, 0, 0);\
  } while (0)

// ---------------- NT GEMM: C[M,N] = A[M,K] @ B[N,K]^T ----------------
// kmode: 0 plain, 2 causal PV (truncate K at m0+128).
// flat: 1-D grid, XCD-chunked, matrix index fastest.
template <bool OUT_BF16>
__global__ __launch_bounds__(256) void gemm_nt(
    const u16* __restrict__ A, long long sA, int lda,
    const u16* __restrict__ B, long long sB, int ldb,
    void* __restrict__ Cv, long long sC, int ldc,
    int K, int kmode,
    int nmat, int ntn, int flat, long long sBm, long long sCm) {
  int n0, m0, mat = 0;
  if (flat) {
    u32 wg = blockIdx.x;
    u32 nchunk = gridDim.x >> 3;
    u32 swz = (wg & 7u) * nchunk + (wg >> 3);
    mat = (int)(swz % (u32)nmat);
    u32 t = swz / (u32)nmat;
    n0 = (int)(t % (u32)ntn) * 128;
    m0 = (int)(t / (u32)ntn) * 128;
  } else {
    n0 = blockIdx.x * 128;
    m0 = blockIdx.y * 128;
  }
  const int z = blockIdx.z;
  const int kEnd = (kmode == 2) ? (m0 + 128) : K;

  A += (size_t)z * sA;
  B += (size_t)z * sB + (size_t)mat * sBm;

  __shared__ alignas(16) u16 As[2][128 * 32];
  __shared__ alignas(16) u16 Bs[2][128 * 32];

  const int tid = threadIdx.x;
  const int lane = tid & 63, wave = tid >> 6;
  const int wm = (wave >> 1) * 64, wn = (wave & 1) * 64;
  const int fr = lane & 15, kc = (lane >> 4) * 8;

  const u16* ga0 = A + (size_t)(m0 + (tid >> 2)) * lda + (tid & 3) * 8;
  const u16* ga1 = ga0 + (size_t)64 * lda;
  const u16* gb0 = B + (size_t)(n0 + (tid >> 2)) * ldb + (tid & 3) * 8;
  const u16* gb1 = gb0 + (size_t)64 * ldb;
  const u32 lo = (u32)(wave * 1024);

  f32x4 acc[4][4];
#pragma unroll
  for (int m = 0; m < 4; ++m)
#pragma unroll
    for (int n = 0; n < 4; ++n)
#pragma unroll
      for (int j = 0; j < 4; ++j) acc[m][n][j] = 0.f;

  const int nt = kEnd >> 5;
  STAGE4(&As[0][0], &Bs[0][0], 0);
  for (int t = 0; t < nt; ++t) {
    __syncthreads();
    if (t + 1 < nt) STAGE4(&As[(t + 1) & 1][0], &Bs[(t + 1) & 1][0], (t + 1) * 32);
    const u16* as = &As[t & 1][0];
    const u16* bs = &Bs[t & 1][0];
    bf16x8 af[4], bfr[4];
#pragma unroll
    for (int m = 0; m < 4; ++m)
      af[m] = *(const bf16x8*)&as[(wm + m * 16 + fr) * 32 + kc];
#pragma unroll
    for (int n = 0; n < 4; ++n)
      bfr[n] = *(const bf16x8*)&bs[(wn + n * 16 + fr) * 32 + kc];
#pragma unroll
    for (int m = 0; m < 4; ++m)
#pragma unroll
      for (int n = 0; n < 4; ++n)
        acc[m][n] = __builtin_amdgcn_mfma_f32_16x16x32_bf16(af[m], bfr[n],
                                                            acc[m][n], 0, 0, 0);
  }

  const int col = lane & 15, rb = (lane >> 4) * 4;
  if (OUT_BF16) {
    u16* C = (u16*)Cv + (size_t)z * sC + (size_t)mat * sCm;
#pragma unroll
    for (int m = 0; m < 4; ++m)
#pragma unroll
      for (int n = 0; n < 4; ++n)
#pragma unroll
        for (int j = 0; j < 4; ++j)
          C[(size_t)(m0 + wm + m * 16 + rb + j) * ldc + (n0 + wn + n * 16 + col)] =
              f2bf(acc[m][n][j]);
  } else {
    float* C = (float*)Cv + (size_t)z * sC + (size_t)mat * sCm;
#pragma unroll
    for (int m = 0; m < 4; ++m)
#pragma unroll
      for (int n = 0; n < 4; ++n)
#pragma unroll
        for (int j = 0; j < 4; ++j)
          C[(size_t)(m0 + wm + m * 16 + rb + j) * ldc + (n0 + wn + n * 16 + col)] =
              acc[m][n][j];
  }
}

// ---------------- snapshot QK sweep ----------------
// C = A[M,1024-slice] @ B^T, causal tile skip. Snapshot acc*scale -> bf16 at
// K=512 (snapA) and K=1024 (snapB). Optional init: acc = bf2f(initSrc)*initScale.
__global__ __launch_bounds__(256) void qk_mega(
    const u16* __restrict__ A, const u16* __restrict__ B,
    u16* __restrict__ snapA, u16* __restrict__ snapB,
    float scaleA, float scaleB,
    const u16* __restrict__ initSrc, float initScale) {
  const int lda = 2048;
  const int m0 = blockIdx.y * 128, n0 = blockIdx.x * 128;
  if (n0 >= m0 + 128) return;  // fully masked tile
  const size_t zWE = (size_t)blockIdx.z * 4194304ull;

  __shared__ alignas(16) u16 As[2][128 * 32];
  __shared__ alignas(16) u16 Bs[2][128 * 32];

  const int tid = threadIdx.x;
  const int lane = tid & 63, wave = tid >> 6;
  const int wm = (wave >> 1) * 64, wn = (wave & 1) * 64;
  const int fr = lane & 15, kc = (lane >> 4) * 8;
  const int col = lane & 15, rb = (lane >> 4) * 4;

  const u16* ga0 = A + zWE + (size_t)(m0 + (tid >> 2)) * lda + (tid & 3) * 8;
  const u16* ga1 = ga0 + (size_t)64 * lda;
  const u16* gb0 = B + zWE + (size_t)(n0 + (tid >> 2)) * lda + (tid & 3) * 8;
  const u16* gb1 = gb0 + (size_t)64 * lda;
  const u32 lo = (u32)(wave * 1024);

  f32x4 acc[4][4];
  if (initSrc) {
    const u16* ip = initSrc + zWE;
#pragma unroll
    for (int m = 0; m < 4; ++m)
#pragma unroll
      for (int n = 0; n < 4; ++n)
#pragma unroll
        for (int j = 0; j < 4; ++j)
          acc[m][n][j] = bf2f(ip[(size_t)(m0 + wm + m * 16 + rb + j) * 2048 +
                                 (n0 + wn + n * 16 + col)]) * initScale;
  } else {
#pragma unroll
    for (int m = 0; m < 4; ++m)
#pragma unroll
      for (int n = 0; n < 4; ++n)
#pragma unroll
        for (int j = 0; j < 4; ++j) acc[m][n][j] = 0.f;
  }

#define SNAPW(ptr, scl)                                                                \
  do {                                                                                 \
    u16* sp = (ptr) + zWE;                                                             \
    _Pragma("unroll") for (int m = 0; m < 4; ++m)                                      \
    _Pragma("unroll") for (int n = 0; n < 4; ++n)                                      \
    _Pragma("unroll") for (int j = 0; j < 4; ++j)                                      \
        sp[(size_t)(m0 + wm + m * 16 + rb + j) * 2048 + (n0 + wn + n * 16 + col)] =    \
            f2bf(acc[m][n][j] * (scl));                                                \
  } while (0)

  STAGE4(&As[0][0], &Bs[0][0], 0);
  for (int t = 0; t < 32; ++t) {
    __syncthreads();
    if (t + 1 < 32) STAGE4(&As[(t + 1) & 1][0], &Bs[(t + 1) & 1][0], (t + 1) * 32);
    const u16* as = &As[t & 1][0];
    const u16* bs = &Bs[t & 1][0];
    bf16x8 af[4], bfr[4];
#pragma unroll
    for (int m = 0; m < 4; ++m)
      af[m] = *(const bf16x8*)&as[(wm + m * 16 + fr) * 32 + kc];
#pragma unroll
    for (int n = 0; n < 4; ++n)
      bfr[n] = *(const bf16x8*)&bs[(wn + n * 16 + fr) * 32 + kc];
#pragma unroll
    for (int m = 0; m < 4; ++m)
#pragma unroll
      for (int n = 0; n < 4; ++n)
        acc[m][n] = __builtin_amdgcn_mfma_f32_16x16x32_bf16(af[m], bfr[n],
                                                            acc[m][n], 0, 0, 0);
    if (t == 15) SNAPW(snapA, scaleA);  // K=512 prefix done
  }
  SNAPW(snapB, scaleB);
#undef SNAPW
}

// ---------------- causal row softmax on scaled bf16 logits ----------------
__global__ __launch_bounds__(256) void softmax_causal(const u16* __restrict__ in,
                                                      u16* __restrict__ out) {
  const int S = 2048;
  const size_t WEz = (size_t)S * S * blockIdx.y;
  const int r = blockIdx.x;
  const int tid = threadIdx.x;
  const int lane = tid & 63, wave = tid >> 6;
  const int c0 = tid * 8;
  const int nvalid = r + 1;
  const u16* rowp = in + WEz + (size_t)r * S;

  float x[8];
  if (c0 < nvalid) {
    U16x8 a = *(const U16x8*)(rowp + c0);
#pragma unroll
    for (int i = 0; i < 8; ++i) x[i] = bf2f(a.v[i]);
  } else {
#pragma unroll
    for (int i = 0; i < 8; ++i) x[i] = 0.f;
  }

  float mx = -3e38f;
#pragma unroll
  for (int i = 0; i < 8; ++i)
    if (c0 + i < nvalid) mx = fmaxf(mx, x[i]);
#pragma unroll
  for (int off = 32; off > 0; off >>= 1) mx = fmaxf(mx, __shfl_xor(mx, off));
  __shared__ float redm[4], reds[4];
  if (lane == 0) redm[wave] = mx;
  __syncthreads();
  mx = fmaxf(fmaxf(redm[0], redm[1]), fmaxf(redm[2], redm[3]));

  float e[8], sum = 0.f;
#pragma unroll
  for (int i = 0; i < 8; ++i) {
    e[i] = (c0 + i < nvalid) ? __expf(x[i] - mx) : 0.f;
    sum += e[i];
  }
#pragma unroll
  for (int off = 32; off > 0; off >>= 1) sum += __shfl_xor(sum, off);
  if (lane == 0) reds[wave] = sum;
  __syncthreads();
  sum = reds[0] + reds[1] + reds[2] + reds[3];
  float inv = 1.f / sum;

  U16x8 w;
#pragma unroll
  for (int i = 0; i < 8; ++i) w.v[i] = f2bf(e[i] * inv);
  *(U16x8*)(out + WEz + (size_t)r * S + c0) = w;
}

// ---------------- launcher ----------------
extern "C" void kernel_launch(void* const* d_in, const int* in_sizes, int n_in,
                              void* d_out, int out_size, void* d_ws, size_t ws_size,
                              hipStream_t stream) {
  (void)in_sizes; (void)n_in; (void)out_size; (void)ws_size;
  const float* x  = (const float*)d_in[0];
  // d_in[1] is the boolean causal mask; causality is hard-coded.
  const float* Wq = (const float*)d_in[2];
  const float* Wk = (const float*)d_in[3];
  const float* Wv = (const float*)d_in[4];
  const float* Wo = (const float*)d_in[5];
  float* out = (float*)d_out;

  char* w = (char*)d_ws;
  const size_t R  = 33554432ull;
  const long long WE = 4194304LL;   // 2048*2048 elems

  u16* xb  = (u16*)(w);
  u16* wT  = (u16*)(w + R);
  u16* wqT = wT;
  u16* woT = wT + 3 * WE;
  u16* q   = (u16*)(w + 2 * R);
  u16* kk  = (u16*)(w + 3 * R);
  u16* v   = (u16*)(w + 4 * R);
  u16* vT  = (u16*)(w + 5 * R);
  u16* o   = v;                      // v dead after transpose
  u16* attnx = xb;                   // xb dead after projections
  u16* slot0 = (u16*)d_out;          // 16.8M elems (4 batches x S x S bf16)
  u16* slot1 = slot0 + 16777216ull;  // second half of d_out

  const float sc0 = 1.0f / sqrtf(512.0f);
  const float sc1 = 1.0f / sqrtf(1024.0f);
  const float sc2 = 1.0f / sqrtf(1536.0f);
  const float sc3 = 1.0f / sqrtf(2048.0f);

  // 1) x -> bf16; weights -> transposed bf16
  conv_f32_bf16<<<8192, 256, 0, stream>>>(x, xb);
  transpose_conv4<<<dim3(64, 64, 4), 256, 0, stream>>>(Wq, Wk, Wv, Wo, wT);
  // 2) fused q,k,v projection (flat XCD-chunked, matrix fastest)
  gemm_nt<true><<<dim3(3072), 256, 0, stream>>>(
      xb, 0LL, 2048, wqT, 0LL, 2048, q, 0LL, 2048, 2048, 0,
      3, 16, 1, WE, 16777216LL);
  // 3) v -> vT
  transpose_bf16<<<dim3(64, 64, 4), 256, 0, stream>>>(v, vT);
  // 4) pass A: K=0..1024, snapshots -> slot0 (slice0 scaled), slot1 (slice1)
  qk_mega<<<dim3(16, 16, 4), 256, 0, stream>>>(q, kk, slot0, slot1, sc0, sc1,
                                               nullptr, 0.f);
  // slice 0: softmax in-place in slot0, then PV
  softmax_causal<<<dim3(2048, 4), 256, 0, stream>>>(slot0, slot0);
  gemm_nt<true><<<dim3(4, 16, 4), 256, 0, stream>>>(
      slot0, WE, 2048, vT, WE, 2048, o, WE, 2048, 2048, 2, 1, 4, 0, 0LL, 0LL);
  // slice 1: softmax slot1 -> xb (slot1 must stay intact for pass-B init)
  softmax_causal<<<dim3(2048, 4), 256, 0, stream>>>(slot1, attnx);
  gemm_nt<true><<<dim3(4, 16, 4), 256, 0, stream>>>(
      attnx, WE, 2048, vT + 1048576, WE, 2048, o + 512, WE, 2048, 2048, 2,
      1, 4, 0, 0LL, 0LL);
  // 5) pass B: K=1024..2048, init from slot1 (* sqrt(1024)), snapshots slices 2,3
  qk_mega<<<dim3(16, 16, 4), 256, 0, stream>>>(q + 1024, kk + 1024, slot0, slot1,
                                               sc2, sc3, slot1, 32.0f);
  softmax_causal<<<dim3(2048, 4), 256, 0, stream>>>(slot0, slot0);
  gemm_nt<true><<<dim3(4, 16, 4), 256, 0, stream>>>(
      slot0, WE, 2048, vT + 2 * 1048576, WE, 2048, o + 1024, WE, 2048, 2048, 2,
      1, 4, 0, 0LL, 0LL);
  softmax_causal<<<dim3(2048, 4), 256, 0, stream>>>(slot1, slot1);
  gemm_nt<true><<<dim3(4, 16, 4), 256, 0, stream>>>(
      slot1, WE, 2048, vT + 3 * 1048576, WE, 2048, o + 1536, WE, 2048, 2048, 2,
      1, 4, 0, 0LL, 0LL);
  // 6) out = o @ Wo (overwrites all of d_out)
  gemm_nt<false><<<dim3(1024), 256, 0, stream>>>(
      o, 0LL, 2048, woT, 0LL, 2048, out, 0LL, 2048, 2048, 0,
      1, 16, 1, 0LL, 0LL);
}

// Round 4
// 649.129 us; speedup vs baseline: 1.6467x; 1.0814x over previous
//
#include <hip/hip_runtime.h>

// MMHSA Matryoshka attention, B=4, S=2048, D=2048, slices {512,1024,1536,2048}.
// Big GEMMs (QKV proj, final proj): 256^2-tile deep-pipelined bf16 MFMA kernel
// (ring-4 BK=32 LDS, counted vmcnt(8), setprio, XOR bank-swizzle, XCD swizzle).
// Attention: 2-pass snapshot QK sweep + bf16 softmax + 128^2 PV (m97 structure).
//
// Workspace (R = 32 MiB, 6R = 201.3 MB):
//   [0,R):    xb (bf16 x)          -> attn scratch for slice 1
//   [R,2R):   wqT wkT wvT woT bf16
//   [2R,3R):  q   [3R,4R): k   [4R,5R): v -> o   [5R,6R): vT
// bf16 snapshots live in d_out (slot0/slot1) until the final GEMM.

typedef __attribute__((ext_vector_type(8))) short bf16x8;
typedef __attribute__((ext_vector_type(4))) float f32x4;
typedef unsigned short u16;
typedef unsigned int u32;

__device__ __forceinline__ u16 f2bf(float f) {
  union { float f; u32 u; } v; v.f = f;
  u32 r = v.u + 0x7fffu + ((v.u >> 16) & 1u);
  return (u16)(r >> 16);
}
__device__ __forceinline__ float bf2f(u16 b) {
  union { u32 u; float f; } v; v.u = ((u32)b) << 16;
  return v.f;
}
struct alignas(16) U16x8 { u16 v[8]; };

#define GLDS(gp, lp)                                                      \
  __builtin_amdgcn_global_load_lds(                                       \
      (const __attribute__((address_space(1))) void*)(gp),                \
      (__attribute__((address_space(3))) void*)(lp), 16, 0, 0)

// ---------------- conversion / transpose kernels ----------------

__global__ __launch_bounds__(256) void conv_f32_bf16(const float* __restrict__ in,
                                                     u16* __restrict__ out) {
  size_t i = ((size_t)blockIdx.x * 256 + threadIdx.x) * 8;
  float4 a = *(const float4*)(in + i);
  float4 b = *(const float4*)(in + i + 4);
  U16x8 w;
  w.v[0] = f2bf(a.x); w.v[1] = f2bf(a.y); w.v[2] = f2bf(a.z); w.v[3] = f2bf(a.w);
  w.v[4] = f2bf(b.x); w.v[5] = f2bf(b.y); w.v[6] = f2bf(b.z); w.v[7] = f2bf(b.w);
  *(U16x8*)(out + i) = w;
}

__global__ __launch_bounds__(256) void transpose_conv4(const float* __restrict__ W0,
                                                       const float* __restrict__ W1,
                                                       const float* __restrict__ W2,
                                                       const float* __restrict__ W3,
                                                       u16* __restrict__ out) {
  const int D = 2048;
  const float* in = (blockIdx.z == 0) ? W0 : (blockIdx.z == 1) ? W1
                  : (blockIdx.z == 2) ? W2 : W3;
  u16* o = out + (size_t)blockIdx.z * D * D;
  __shared__ float t[32][33];
  int bx = blockIdx.x * 32, by = blockIdx.y * 32;
  int tx = threadIdx.x & 31, ty = threadIdx.x >> 5;
#pragma unroll
  for (int i = 0; i < 32; i += 8)
    t[ty + i][tx] = in[(size_t)(by + ty + i) * D + bx + tx];
  __syncthreads();
#pragma unroll
  for (int i = 0; i < 32; i += 8)
    o[(size_t)(bx + ty + i) * D + by + tx] = f2bf(t[tx][ty + i]);
}

__global__ __launch_bounds__(256) void transpose_bf16(const u16* __restrict__ in,
                                                      u16* __restrict__ out) {
  const int D = 2048;
  size_t zoff = (size_t)blockIdx.z * D * D;
  in += zoff; out += zoff;
  __shared__ u16 t[32][34];
  int bx = blockIdx.x * 32, by = blockIdx.y * 32;
  int tx = threadIdx.x & 31, ty = threadIdx.x >> 5;
#pragma unroll
  for (int i = 0; i < 32; i += 8)
    t[ty + i][tx] = in[(size_t)(by + ty + i) * D + bx + tx];
  __syncthreads();
#pragma unroll
  for (int i = 0; i < 32; i += 8)
    out[(size_t)(bx + ty + i) * D + by + tx] = t[tx][ty + i];
}

// ============ 256^2 deep-pipelined NT GEMM: C[M,N] = A[M,K] @ B[N,K]^T ============
// 512 threads, 8 waves (2M x 4N), per-wave output 128x64. Ring-4 of BK=32 K-tiles
// in LDS (4 x 16KB per matrix = 128 KB total, dynamic). Per K-tile: 2 phases of
// 16 MFMA; stage A(t+3) in phase 1, B(t+3) in phase 2; vmcnt(8) once per tile.
// LDS bank swizzle: 16B slot s at row r holds global slot s ^ ((r>>1)&3).
// Requires K % 32 == 0, K/32 >= 4, M,N multiples of 256, grid.x % 8 == 0.
template <bool OUT_BF16>
__global__ __launch_bounds__(512, 2) void gemm256(
    const u16* __restrict__ A, int lda,
    const u16* __restrict__ B, int ldb,
    void* __restrict__ Cv, int ldc,
    int K, int nmat, int ntn, long long sBm, long long sCm) {
  extern __shared__ char smem[];
  u16* const As = (u16*)smem;             // [4][256*32] u16 (16 KB per slot)
  u16* const Bs = (u16*)(smem + 65536);

  // flat XCD-chunked swizzle, matrix index fastest
  u32 wg = blockIdx.x;
  u32 nchunk = gridDim.x >> 3;
  u32 swz = (wg & 7u) * nchunk + (wg >> 3);
  const int mat = (int)(swz % (u32)nmat);
  u32 t = swz / (u32)nmat;
  const int n0 = (int)(t % (u32)ntn) * 256;
  const int m0 = (int)(t / (u32)ntn) * 256;

  B += (size_t)mat * sBm;

  const int tid = threadIdx.x;
  const int lane = tid & 63, wave = tid >> 6;
  const int wm = (wave >> 2) * 128;       // 0 or 128
  const int wn = (wave & 3) * 64;         // 0,64,128,192
  const int fr = lane & 15, kgrp = lane >> 4;
  const u32 lo = (u32)(wave * 1024);      // wave-uniform LDS chunk for staging

  // staging map: thread covers LDS row srow (and srow+128), 16B slot (tid&3);
  // pre-swizzled global source slot ssl so LDS stays linear (rule #21)
  const int srow = tid >> 2;
  const int ssl = (tid & 3) ^ ((srow >> 1) & 3);
  const u16* gA0 = A + (size_t)(m0 + srow) * lda + ssl * 8;
  const u16* gA1 = gA0 + (size_t)128 * lda;
  const u16* gB0 = B + (size_t)(n0 + srow) * ldb + ssl * 8;
  const u16* gB1 = gB0 + (size_t)128 * ldb;

  // ds_read swizzled k-offset (u16 units): slot kgrp at row -> pos kgrp ^ ((row>>1)&3)
  const int koe = (kgrp ^ ((fr >> 1) & 3)) * 8;

#define STG_A(slot, kOff) do {                                            \
    char* lb = (char*)As + (slot) * 16384 + lo;                           \
    GLDS(gA0 + (kOff), lb);                                               \
    GLDS(gA1 + (kOff), lb + 8192);                                        \
  } while (0)
#define STG_B(slot, kOff) do {                                            \
    char* lb = (char*)Bs + (slot) * 16384 + lo;                           \
    GLDS(gB0 + (kOff), lb);                                               \
    GLDS(gB1 + (kOff), lb + 8192);                                        \
  } while (0)

  f32x4 acc[8][4];
#pragma unroll
  for (int m = 0; m < 8; ++m)
#pragma unroll
    for (int n = 0; n < 4; ++n)
#pragma unroll
      for (int j = 0; j < 4; ++j) acc[m][n][j] = 0.f;

  const int NT = K >> 5;
  // prologue: stage tiles 0,1,2 (12 loads); wait own oldest 4 (tile 0); barrier
  STG_A(0, 0);  STG_B(0, 0);
  STG_A(1, 32); STG_B(1, 32);
  STG_A(2, 64); STG_B(2, 64);
  asm volatile("s_waitcnt vmcnt(8)" ::: "memory");
  __builtin_amdgcn_s_barrier();

  for (int tt = 0; tt < NT; ++tt) {
    const int sl = tt & 3;
    const u16* as = As + sl * 8192;       // u16 units
    const u16* bs = Bs + sl * 8192;
    const int kOf = (tt + 3) * 32;
    const bool stg = (tt + 3) < NT;
    bf16x8 afrag[4], bfrag[4];

    // ---- phase 1: B-frags + A-frags 0-3; stage A(t+3); 16 MFMA ----
#pragma unroll
    for (int n = 0; n < 4; ++n)
      bfrag[n] = *(const bf16x8*)&bs[((wn + n * 16 + fr) << 5) + koe];
#pragma unroll
    for (int m = 0; m < 4; ++m)
      afrag[m] = *(const bf16x8*)&as[((wm + m * 16 + fr) << 5) + koe];
    if (stg) STG_A((tt + 3) & 3, kOf);
    __builtin_amdgcn_s_barrier();
    __builtin_amdgcn_s_setprio(1);
#pragma unroll
    for (int m = 0; m < 4; ++m)
#pragma unroll
      for (int n = 0; n < 4; ++n)
        acc[m][n] = __builtin_amdgcn_mfma_f32_16x16x32_bf16(afrag[m], bfrag[n],
                                                            acc[m][n], 0, 0, 0);
    __builtin_amdgcn_s_setprio(0);
    __builtin_amdgcn_s_barrier();

    // ---- phase 2: A-frags 4-7; stage B(t+3); counted vmcnt; 16 MFMA ----
#pragma unroll
    for (int m = 0; m < 4; ++m)
      afrag[m] = *(const bf16x8*)&as[((wm + (m + 4) * 16 + fr) << 5) + koe];
    if (stg) STG_B((tt + 3) & 3, kOf);
    if (tt + 3 < NT)       asm volatile("s_waitcnt vmcnt(8)" ::: "memory");
    else if (tt + 3 == NT) asm volatile("s_waitcnt vmcnt(4)" ::: "memory");
    else                   asm volatile("s_waitcnt vmcnt(0)" ::: "memory");
    __builtin_amdgcn_s_barrier();
    __builtin_amdgcn_s_setprio(1);
#pragma unroll
    for (int m = 0; m < 4; ++m)
#pragma unroll
      for (int n = 0; n < 4; ++n)
        acc[m + 4][n] = __builtin_amdgcn_mfma_f32_16x16x32_bf16(afrag[m], bfrag[n],
                                                                acc[m + 4][n], 0, 0, 0);
    __builtin_amdgcn_s_setprio(0);
    __builtin_amdgcn_s_barrier();
  }
#undef STG_A
#undef STG_B

  // epilogue: C/D layout col = lane&15, row = (lane>>4)*4 + j
  const int cl = lane & 15, rb = (lane >> 4) * 4;
  if (OUT_BF16) {
    u16* C = (u16*)Cv + (size_t)mat * sCm;
#pragma unroll
    for (int m = 0; m < 8; ++m)
#pragma unroll
      for (int n = 0; n < 4; ++n)
#pragma unroll
        for (int j = 0; j < 4; ++j)
          C[(size_t)(m0 + wm + m * 16 + rb + j) * ldc + (n0 + wn + n * 16 + cl)] =
              f2bf(acc[m][n][j]);
  } else {
    float* C = (float*)Cv + (size_t)mat * sCm;
#pragma unroll
    for (int m = 0; m < 8; ++m)
#pragma unroll
      for (int n = 0; n < 4; ++n)
#pragma unroll
        for (int j = 0; j < 4; ++j)
          C[(size_t)(m0 + wm + m * 16 + rb + j) * ldc + (n0 + wn + n * 16 + cl)] =
              acc[m][n][j];
  }
}

// ---------------- staging macro for 128^2 kernels (128x32 bf16 tile) ----------------
#define STAGE4(Abuf, Bbuf, kOff)                                                       \
  do {                                                                                 \
    GLDS(ga0 + (kOff), (char*)(Abuf) + lo);                                            \
    GLDS(ga1 + (kOff), (char*)(Abuf) + lo + 4096);                                     \
    GLDS(gb0 + (kOff), (char*)(Bbuf) + lo);                                            \
    GLDS(gb1 + (kOff), (char*)(Bbuf) + lo + 4096);                                     \
  } while (0)

// ---------------- 128^2 NT GEMM (m97 structure) for PV ----------------
// kmode: 0 plain, 2 causal PV (truncate K at m0+128).
template <bool OUT_BF16>
__global__ __launch_bounds__(256) void gemm_nt(
    const u16* __restrict__ A, long long sA, int lda,
    const u16* __restrict__ B, long long sB, int ldb,
    void* __restrict__ Cv, long long sC, int ldc,
    int K, int kmode) {
  const int n0 = blockIdx.x * 128, m0 = blockIdx.y * 128;
  const int z = blockIdx.z;
  const int kEnd = (kmode == 2) ? (m0 + 128) : K;

  A += (size_t)z * sA;
  B += (size_t)z * sB;

  __shared__ alignas(16) u16 As[2][128 * 32];
  __shared__ alignas(16) u16 Bs[2][128 * 32];

  const int tid = threadIdx.x;
  const int lane = tid & 63, wave = tid >> 6;
  const int wm = (wave >> 1) * 64, wn = (wave & 1) * 64;
  const int fr = lane & 15, kc = (lane >> 4) * 8;

  const u16* ga0 = A + (size_t)(m0 + (tid >> 2)) * lda + (tid & 3) * 8;
  const u16* ga1 = ga0 + (size_t)64 * lda;
  const u16* gb0 = B + (size_t)(n0 + (tid >> 2)) * ldb + (tid & 3) * 8;
  const u16* gb1 = gb0 + (size_t)64 * ldb;
  const u32 lo = (u32)(wave * 1024);

  f32x4 acc[4][4];
#pragma unroll
  for (int m = 0; m < 4; ++m)
#pragma unroll
    for (int n = 0; n < 4; ++n)
#pragma unroll
      for (int j = 0; j < 4; ++j) acc[m][n][j] = 0.f;

  const int nt = kEnd >> 5;
  STAGE4(&As[0][0], &Bs[0][0], 0);
  for (int t = 0; t < nt; ++t) {
    __syncthreads();
    if (t + 1 < nt) STAGE4(&As[(t + 1) & 1][0], &Bs[(t + 1) & 1][0], (t + 1) * 32);
    const u16* as = &As[t & 1][0];
    const u16* bs = &Bs[t & 1][0];
    bf16x8 af[4], bfr[4];
#pragma unroll
    for (int m = 0; m < 4; ++m)
      af[m] = *(const bf16x8*)&as[(wm + m * 16 + fr) * 32 + kc];
#pragma unroll
    for (int n = 0; n < 4; ++n)
      bfr[n] = *(const bf16x8*)&bs[(wn + n * 16 + fr) * 32 + kc];
#pragma unroll
    for (int m = 0; m < 4; ++m)
#pragma unroll
      for (int n = 0; n < 4; ++n)
        acc[m][n] = __builtin_amdgcn_mfma_f32_16x16x32_bf16(af[m], bfr[n],
                                                            acc[m][n], 0, 0, 0);
  }

  const int col = lane & 15, rb = (lane >> 4) * 4;
  if (OUT_BF16) {
    u16* C = (u16*)Cv + (size_t)z * sC;
#pragma unroll
    for (int m = 0; m < 4; ++m)
#pragma unroll
      for (int n = 0; n < 4; ++n)
#pragma unroll
        for (int j = 0; j < 4; ++j)
          C[(size_t)(m0 + wm + m * 16 + rb + j) * ldc + (n0 + wn + n * 16 + col)] =
              f2bf(acc[m][n][j]);
  } else {
    float* C = (float*)Cv + (size_t)z * sC;
#pragma unroll
    for (int m = 0; m < 4; ++m)
#pragma unroll
      for (int n = 0; n < 4; ++n)
#pragma unroll
        for (int j = 0; j < 4; ++j)
          C[(size_t)(m0 + wm + m * 16 + rb + j) * ldc + (n0 + wn + n * 16 + col)] =
              acc[m][n][j];
  }
}

// ---------------- snapshot QK sweep (K=1024 per pass, 128^2 tiles) ----------------
__global__ __launch_bounds__(256) void qk_mega(
    const u16* __restrict__ A, const u16* __restrict__ B,
    u16* __restrict__ snapA, u16* __restrict__ snapB,
    float scaleA, float scaleB,
    const u16* __restrict__ initSrc, float initScale) {
  const int lda = 2048;
  const int m0 = blockIdx.y * 128, n0 = blockIdx.x * 128;
  if (n0 >= m0 + 128) return;  // fully masked tile
  const size_t zWE = (size_t)blockIdx.z * 4194304ull;

  __shared__ alignas(16) u16 As[2][128 * 32];
  __shared__ alignas(16) u16 Bs[2][128 * 32];

  const int tid = threadIdx.x;
  const int lane = tid & 63, wave = tid >> 6;
  const int wm = (wave >> 1) * 64, wn = (wave & 1) * 64;
  const int fr = lane & 15, kc = (lane >> 4) * 8;
  const int col = lane & 15, rb = (lane >> 4) * 4;

  const u16* ga0 = A + zWE + (size_t)(m0 + (tid >> 2)) * lda + (tid & 3) * 8;
  const u16* ga1 = ga0 + (size_t)64 * lda;
  const u16* gb0 = B + zWE + (size_t)(n0 + (tid >> 2)) * lda + (tid & 3) * 8;
  const u16* gb1 = gb0 + (size_t)64 * lda;
  const u32 lo = (u32)(wave * 1024);

  f32x4 acc[4][4];
  if (initSrc) {
    const u16* ip = initSrc + zWE;
#pragma unroll
    for (int m = 0; m < 4; ++m)
#pragma unroll
      for (int n = 0; n < 4; ++n)
#pragma unroll
        for (int j = 0; j < 4; ++j)
          acc[m][n][j] = bf2f(ip[(size_t)(m0 + wm + m * 16 + rb + j) * 2048 +
                                 (n0 + wn + n * 16 + col)]) * initScale;
  } else {
#pragma unroll
    for (int m = 0; m < 4; ++m)
#pragma unroll
      for (int n = 0; n < 4; ++n)
#pragma unroll
        for (int j = 0; j < 4; ++j) acc[m][n][j] = 0.f;
  }

#define SNAPW(ptr, scl)                                                                \
  do {                                                                                 \
    u16* sp = (ptr) + zWE;                                                             \
    _Pragma("unroll") for (int m = 0; m < 4; ++m)                                      \
    _Pragma("unroll") for (int n = 0; n < 4; ++n)                                      \
    _Pragma("unroll") for (int j = 0; j < 4; ++j)                                      \
        sp[(size_t)(m0 + wm + m * 16 + rb + j) * 2048 + (n0 + wn + n * 16 + col)] =    \
            f2bf(acc[m][n][j] * (scl));                                                \
  } while (0)

  STAGE4(&As[0][0], &Bs[0][0], 0);
  for (int t = 0; t < 32; ++t) {
    __syncthreads();
    if (t + 1 < 32) STAGE4(&As[(t + 1) & 1][0], &Bs[(t + 1) & 1][0], (t + 1) * 32);
    const u16* as = &As[t & 1][0];
    const u16* bs = &Bs[t & 1][0];
    bf16x8 af[4], bfr[4];
#pragma unroll
    for (int m = 0; m < 4; ++m)
      af[m] = *(const bf16x8*)&as[(wm + m * 16 + fr) * 32 + kc];
#pragma unroll
    for (int n = 0; n < 4; ++n)
      bfr[n] = *(const bf16x8*)&bs[(wn + n * 16 + fr) * 32 + kc];
#pragma unroll
    for (int m = 0; m < 4; ++m)
#pragma unroll
      for (int n = 0; n < 4; ++n)
        acc[m][n] = __builtin_amdgcn_mfma_f32_16x16x32_bf16(af[m], bfr[n],
                                                            acc[m][n], 0, 0, 0);
    if (t == 15) SNAPW(snapA, scaleA);  // K=512 prefix done
  }
  SNAPW(snapB, scaleB);
#undef SNAPW
}

// ---------------- causal row softmax on scaled bf16 logits ----------------
__global__ __launch_bounds__(256) void softmax_causal(const u16* __restrict__ in,
                                                      u16* __restrict__ out) {
  const int S = 2048;
  const size_t WEz = (size_t)S * S * blockIdx.y;
  const int r = blockIdx.x;
  const int tid = threadIdx.x;
  const int lane = tid & 63, wave = tid >> 6;
  const int c0 = tid * 8;
  const int nvalid = r + 1;
  const u16* rowp = in + WEz + (size_t)r * S;

  float x[8];
  if (c0 < nvalid) {
    U16x8 a = *(const U16x8*)(rowp + c0);
#pragma unroll
    for (int i = 0; i < 8; ++i) x[i] = bf2f(a.v[i]);
  } else {
#pragma unroll
    for (int i = 0; i < 8; ++i) x[i] = 0.f;
  }

  float mx = -3e38f;
#pragma unroll
  for (int i = 0; i < 8; ++i)
    if (c0 + i < nvalid) mx = fmaxf(mx, x[i]);
#pragma unroll
  for (int off = 32; off > 0; off >>= 1) mx = fmaxf(mx, __shfl_xor(mx, off));
  __shared__ float redm[4], reds[4];
  if (lane == 0) redm[wave] = mx;
  __syncthreads();
  mx = fmaxf(fmaxf(redm[0], redm[1]), fmaxf(redm[2], redm[3]));

  float e[8], sum = 0.f;
#pragma unroll
  for (int i = 0; i < 8; ++i) {
    e[i] = (c0 + i < nvalid) ? __expf(x[i] - mx) : 0.f;
    sum += e[i];
  }
#pragma unroll
  for (int off = 32; off > 0; off >>= 1) sum += __shfl_xor(sum, off);
  if (lane == 0) reds[wave] = sum;
  __syncthreads();
  sum = reds[0] + reds[1] + reds[2] + reds[3];
  float inv = 1.f / sum;

  U16x8 w;
#pragma unroll
  for (int i = 0; i < 8; ++i) w.v[i] = f2bf(e[i] * inv);
  *(U16x8*)(out + WEz + (size_t)r * S + c0) = w;
}

// ---------------- launcher ----------------
extern "C" void kernel_launch(void* const* d_in, const int* in_sizes, int n_in,
                              void* d_out, int out_size, void* d_ws, size_t ws_size,
                              hipStream_t stream) {
  (void)in_sizes; (void)n_in; (void)out_size; (void)ws_size;
  const float* x  = (const float*)d_in[0];
  // d_in[1] is the boolean causal mask; causality is hard-coded.
  const float* Wq = (const float*)d_in[2];
  const float* Wk = (const float*)d_in[3];
  const float* Wv = (const float*)d_in[4];
  const float* Wo = (const float*)d_in[5];
  float* out = (float*)d_out;

  char* w = (char*)d_ws;
  const size_t R  = 33554432ull;
  const long long WE = 4194304LL;   // 2048*2048 elems

  u16* xb  = (u16*)(w);
  u16* wT  = (u16*)(w + R);
  u16* wqT = wT;
  u16* woT = wT + 3 * WE;
  u16* q   = (u16*)(w + 2 * R);
  u16* kk  = (u16*)(w + 3 * R);
  u16* v   = (u16*)(w + 4 * R);
  u16* vT  = (u16*)(w + 5 * R);
  u16* o   = v;                      // v dead after transpose
  u16* attnx = xb;                   // xb dead after projections
  u16* slot0 = (u16*)d_out;          // 16.8M elems (4 batches x S x S bf16)
  u16* slot1 = slot0 + 16777216ull;  // second half of d_out

  const float sc0 = 1.0f / sqrtf(512.0f);
  const float sc1 = 1.0f / sqrtf(1024.0f);
  const float sc2 = 1.0f / sqrtf(1536.0f);
  const float sc3 = 1.0f / sqrtf(2048.0f);

  // allow 128 KB dynamic LDS on the big-tile GEMM (deterministic, capture-safe)
  hipFuncSetAttribute(reinterpret_cast<const void*>(&gemm256<true>),
                      hipFuncAttributeMaxDynamicSharedMemorySize, 131072);
  hipFuncSetAttribute(reinterpret_cast<const void*>(&gemm256<false>),
                      hipFuncAttributeMaxDynamicSharedMemorySize, 131072);

  // 1) x -> bf16; weights -> transposed bf16
  conv_f32_bf16<<<8192, 256, 0, stream>>>(x, xb);
  transpose_conv4<<<dim3(64, 64, 4), 256, 0, stream>>>(Wq, Wk, Wv, Wo, wT);
  // 2) fused q,k,v projection: M=8192, per-mat N=2048, K=2048, 3 mats
  gemm256<true><<<dim3(768), 512, 131072, stream>>>(
      xb, 2048, wqT, 2048, q, 2048, 2048, 3, 8, WE, 16777216LL);
  // 3) v -> vT
  transpose_bf16<<<dim3(64, 64, 4), 256, 0, stream>>>(v, vT);
  // 4) pass A: K=0..1024, snapshots -> slot0 (slice0), slot1 (slice1)
  qk_mega<<<dim3(16, 16, 4), 256, 0, stream>>>(q, kk, slot0, slot1, sc0, sc1,
                                               nullptr, 0.f);
  softmax_causal<<<dim3(2048, 4), 256, 0, stream>>>(slot0, slot0);
  gemm_nt<true><<<dim3(4, 16, 4), 256, 0, stream>>>(
      slot0, WE, 2048, vT, WE, 2048, o, WE, 2048, 2048, 2);
  softmax_causal<<<dim3(2048, 4), 256, 0, stream>>>(slot1, attnx);
  gemm_nt<true><<<dim3(4, 16, 4), 256, 0, stream>>>(
      attnx, WE, 2048, vT + 1048576, WE, 2048, o + 512, WE, 2048, 2048, 2);
  // 5) pass B: K=1024..2048, init from slot1 (* sqrt(1024)), snapshots slices 2,3
  qk_mega<<<dim3(16, 16, 4), 256, 0, stream>>>(q + 1024, kk + 1024, slot0, slot1,
                                               sc2, sc3, slot1, 32.0f);
  softmax_causal<<<dim3(2048, 4), 256, 0, stream>>>(slot0, slot0);
  gemm_nt<true><<<dim3(4, 16, 4), 256, 0, stream>>>(
      slot0, WE, 2048, vT + 2 * 1048576, WE, 2048, o + 1024, WE, 2048, 2048, 2);
  softmax_causal<<<dim3(2048, 4), 256, 0, stream>>>(slot1, slot1);
  gemm_nt<true><<<dim3(4, 16, 4), 256, 0, stream>>>(
      slot1, WE, 2048, vT + 3 * 1048576, WE, 2048, o + 1536, WE, 2048, 2048, 2);
  // 6) out = o @ Wo: M=8192, N=2048, K=2048
  gemm256<false><<<dim3(256), 512, 131072, stream>>>(
      o, 2048, woT, 2048, out, 2048, 2048, 1, 8, 0LL, 0LL);
}